// Round 2
// baseline (222.060 us; speedup 1.0000x reference)
//
#include <hip/hip_runtime.h>
#include <hip/hip_bf16.h>
#include <math.h>

#define B_N 4096
#define D_N 768
#define C_N 10
#define LDP 72   // padded LDS row stride (elems): 144B = 36 banks -> even spread, 16B aligned

typedef short bf16x8 __attribute__((ext_vector_type(8)));
typedef float f32x4 __attribute__((ext_vector_type(4)));

// ws layout (floats):
//   [0] ce_sum   [1] taml_sum   [2] tals   [3] nvalid
//   [8..18)   counts[10]
//   [32..32+7680)  class sums [10][768]
// byte offset 65536: enorm bf16 [4096*768]  (6291456 bytes)

static __device__ __forceinline__ unsigned short bf16bits(float f, float s) {
    __hip_bfloat16 h = __float2bfloat16(f * s);
    return *(unsigned short*)&h;
}

// ---------------- CE + label histogram ----------------
__global__ void k_ce(const float* __restrict__ logits,
                     const int* __restrict__ labels,
                     float* __restrict__ ws) {
    __shared__ float red[256];
    __shared__ float cnt[C_N];
    int t = threadIdx.x;
    if (t < C_N) cnt[t] = 0.f;
    __syncthreads();

    int row = blockIdx.x * 256 + t;
    int lab = labels[row];
    const float* lp = logits + (size_t)row * C_N;
    float m = lp[0];
#pragma unroll
    for (int c = 1; c < C_N; ++c) m = fmaxf(m, lp[c]);
    float s = 0.f;
#pragma unroll
    for (int c = 0; c < C_N; ++c) s += __expf(lp[c] - m);
    float val = (m + __logf(s)) - lp[lab];   // -log p[label]

    atomicAdd(&cnt[lab], 1.0f);
    red[t] = val;
    __syncthreads();
    for (int off = 128; off; off >>= 1) {
        if (t < off) red[t] += red[t + off];
        __syncthreads();
    }
    if (t == 0) atomicAdd(&ws[0], red[0]);
    if (t < C_N) atomicAdd(&ws[8 + t], cnt[t]);
}

// ---------------- per-class segment sums ----------------
// grid (3, 64): bx = 256-col chunk, by = 64-row chunk.
// Register accumulators (static class indexing) -> no loop-carried LDS dep,
// global loads pipeline freely. labels loads are wave-uniform -> scalar.
__global__ void k_cent(const float* __restrict__ emb,
                       const int* __restrict__ labels,
                       float* __restrict__ ws) {
    int t = threadIdx.x;
    int col = blockIdx.x * 256 + t;
    int rbase = blockIdx.y * 64;
    float a[C_N];
#pragma unroll
    for (int c = 0; c < C_N; ++c) a[c] = 0.f;
    const float* p = emb + (size_t)rbase * D_N + col;
#pragma unroll 4
    for (int rr = 0; rr < 64; ++rr) {
        int lab = labels[rbase + rr];
        float v = p[(size_t)rr * D_N];
#pragma unroll
        for (int c = 0; c < C_N; ++c) a[c] += (lab == c) ? v : 0.f;
    }
    float* sums = ws + 32;
#pragma unroll
    for (int c = 0; c < C_N; ++c) atomicAdd(&sums[c * D_N + col], a[c]);
}

// ---------------- row-normalize -> bf16 ----------------
// wave per row: no barriers, no LDS. float4 loads, shfl butterfly, ushort4 stores.
__global__ void k_enorm(const float* __restrict__ emb,
                        __hip_bfloat16* __restrict__ enorm) {
    int t = threadIdx.x;
    int w = t >> 6, lane = t & 63;
    int row = blockIdx.x * 4 + w;
    const float4* src = (const float4*)(emb + (size_t)row * D_N);
    float4 x0 = src[lane];
    float4 x1 = src[lane + 64];
    float4 x2 = src[lane + 128];
    float ss = x0.x * x0.x + x0.y * x0.y + x0.z * x0.z + x0.w * x0.w
             + x1.x * x1.x + x1.y * x1.y + x1.z * x1.z + x1.w * x1.w
             + x2.x * x2.x + x2.y * x2.y + x2.z * x2.z + x2.w * x2.w;
#pragma unroll
    for (int off = 32; off; off >>= 1) ss += __shfl_xor(ss, off, 64);
    float inv = 1.0f / fmaxf(sqrtf(ss), 1e-12f);
    ushort4* dst = (ushort4*)(enorm + (size_t)row * D_N);
    ushort4 u0, u1, u2;
    u0.x = bf16bits(x0.x, inv); u0.y = bf16bits(x0.y, inv);
    u0.z = bf16bits(x0.z, inv); u0.w = bf16bits(x0.w, inv);
    u1.x = bf16bits(x1.x, inv); u1.y = bf16bits(x1.y, inv);
    u1.z = bf16bits(x1.z, inv); u1.w = bf16bits(x1.w, inv);
    u2.x = bf16bits(x2.x, inv); u2.y = bf16bits(x2.y, inv);
    u2.z = bf16bits(x2.z, inv); u2.w = bf16bits(x2.w, inv);
    dst[lane]       = u0;
    dst[lane + 64]  = u1;
    dst[lane + 128] = u2;
}

// ---------------- fused TAML GEMM ----------------
// 128x128 tile, BK=64, padded LDS, register-prefetch software pipeline.
__global__ __launch_bounds__(256) void k_taml(const __hip_bfloat16* __restrict__ E,
                                              const int* __restrict__ labels,
                                              const float* __restrict__ topo,
                                              float* __restrict__ ws) {
    int bi = blockIdx.y, bj = blockIdx.x;
    if (bj < bi) return;   // uniform exit, before any barrier

    __shared__ __hip_bfloat16 As[128 * LDP];
    __shared__ __hip_bfloat16 Bs[128 * LDP];
    __shared__ int lA[128], lB[128];
    __shared__ float topo_s[C_N * C_N];
    __shared__ float wsum[4];

    int t = threadIdx.x;
    int ib0 = bi * 128, jb0 = bj * 128;
    if (t < 128) lA[t] = labels[ib0 + t];
    else         lB[t - 128] = labels[jb0 + t - 128];
    if (t < C_N * C_N) topo_s[t] = topo[t];

    int w = t >> 6, lane = t & 63;
    int quad = lane >> 4, m16 = lane & 15;
    int wrow = (w >> 1) * 64, wcol = (w & 1) * 64;

    f32x4 acc[4][4];
    f32x4 z = {0.f, 0.f, 0.f, 0.f};
#pragma unroll
    for (int mt = 0; mt < 4; ++mt)
#pragma unroll
        for (int nt = 0; nt < 4; ++nt) acc[mt][nt] = z;

    // staging: thread covers row r = t>>1, col half h = t&1 (32 elems = 4 float4)
    int r = t >> 1, h = t & 1;
    const float4* gA = (const float4*)(E + (size_t)(ib0 + r) * D_N + h * 32);
    const float4* gB = (const float4*)(E + (size_t)(jb0 + r) * D_N + h * 32);
    float4* wA = (float4*)(As + r * LDP + h * 32);
    float4* wB = (float4*)(Bs + r * LDP + h * 32);

    float4 pa[4], pb[4];
#pragma unroll
    for (int x = 0; x < 4; ++x) { pa[x] = gA[x]; pb[x] = gB[x]; }
#pragma unroll
    for (int x = 0; x < 4; ++x) { wA[x] = pa[x]; wB[x] = pb[x]; }

    for (int kt = 0; kt < 12; ++kt) {
        __syncthreads();
        if (kt < 11) {
            const float4* ga = gA + (kt + 1) * 8;   // 64 elems = 8 float4
            const float4* gb = gB + (kt + 1) * 8;
#pragma unroll
            for (int x = 0; x < 4; ++x) { pa[x] = ga[x]; pb[x] = gb[x]; }
        }
#pragma unroll
        for (int ks = 0; ks < 2; ++ks) {
            bf16x8 af[4], bfr[4];
#pragma unroll
            for (int x = 0; x < 4; ++x) {
                af[x]  = *(const bf16x8*)(As + (wrow + x * 16 + m16) * LDP + ks * 32 + quad * 8);
                bfr[x] = *(const bf16x8*)(Bs + (wcol + x * 16 + m16) * LDP + ks * 32 + quad * 8);
            }
#pragma unroll
            for (int mt = 0; mt < 4; ++mt)
#pragma unroll
                for (int nt = 0; nt < 4; ++nt)
                    acc[mt][nt] = __builtin_amdgcn_mfma_f32_16x16x32_bf16(
                        af[mt], bfr[nt], acc[mt][nt], 0, 0, 0);
        }
        __syncthreads();
        if (kt < 11) {
#pragma unroll
            for (int x = 0; x < 4; ++x) { wA[x] = pa[x]; wB[x] = pb[x]; }
        }
    }

    // epilogue: relu(sim - 1 + margin) over valid (li!=lj) upper-tri pairs, x2
    float local = 0.f;
#pragma unroll
    for (int mt = 0; mt < 4; ++mt) {
#pragma unroll
        for (int nt = 0; nt < 4; ++nt) {
#pragma unroll
            for (int reg = 0; reg < 4; ++reg) {
                int il = wrow + mt * 16 + quad * 4 + reg;
                int jl = wcol + nt * 16 + m16;
                int gi = ib0 + il, gj = jb0 + jl;
                int li = lA[il], lj = lB[jl];
                float v = acc[mt][nt][reg] - 1.0f + topo_s[li * C_N + lj];
                if (li != lj && gi < gj && v > 0.f) local += v;
            }
        }
    }
    local *= 2.0f;

#pragma unroll
    for (int off = 32; off; off >>= 1) local += __shfl_down(local, off, 64);
    if (lane == 0) wsum[w] = local;
    __syncthreads();
    if (t == 0) atomicAdd(&ws[1], wsum[0] + wsum[1] + wsum[2] + wsum[3]);
}

// ---------------- TALS + nvalid + final combine ----------------
__global__ void k_tals(const float* __restrict__ topo, float* __restrict__ ws,
                       float* __restrict__ out) {
    __shared__ float cents[C_N * 769];
    __shared__ float edist[C_N * C_N];
    __shared__ float cnt_s[C_N];
    int t = threadIdx.x;   // 128 threads
    const float* counts = ws + 8;
    const float* sums = ws + 32;
    if (t < C_N) cnt_s[t] = counts[t];
    __syncthreads();
    for (int idx = t; idx < C_N * D_N; idx += 128) {
        int c = idx / D_N, d = idx - c * D_N;
        cents[c * 769 + d] = sums[idx] / fmaxf(cnt_s[c], 1.0f);
    }
    __syncthreads();
    if (t < C_N * C_N) {
        int i = t / C_N, j = t - (t / C_N) * C_N;
        float s = 0.f;
        for (int d = 0; d < D_N; ++d) {
            float diff = cents[i * 769 + d] - cents[j * 769 + d];
            s += diff * diff;
        }
        edist[t] = sqrtf(s + 1e-12f);
    }
    __syncthreads();
    if (t == 0) {
        float mx = 0.f;
        for (int p = 0; p < C_N * C_N; ++p) mx = fmaxf(mx, edist[p]);
        float inv = 1.0f / (mx + 1e-8f);
        float accv = 0.f;
        for (int p = 0; p < C_N * C_N; ++p) {
            float d = edist[p] * inv - topo[p];
            accv += d * d;
        }
        float tals = accv * (1.0f / (C_N * C_N));
        float s2 = 0.f;
        for (int c = 0; c < C_N; ++c) s2 += cnt_s[c] * cnt_s[c];
        float nvalid = (float)B_N * (float)B_N - s2;
        float ce   = ws[0] / (float)B_N;
        float taml = ws[1] / fmaxf(nvalid, 1.0f);
        out[0] = ce + 0.5f * tals + 0.5f * taml;
        out[1] = ce;
        out[2] = tals;
        out[3] = taml;
    }
}

extern "C" void kernel_launch(void* const* d_in, const int* in_sizes, int n_in,
                              void* d_out, int out_size, void* d_ws, size_t ws_size,
                              hipStream_t stream) {
    const float* logits = (const float*)d_in[0];
    const int*   labels = (const int*)d_in[1];
    const float* emb    = (const float*)d_in[2];
    const float* topo   = (const float*)d_in[3];
    float* ws = (float*)d_ws;
    __hip_bfloat16* enorm = (__hip_bfloat16*)((char*)d_ws + 65536);
    float* out = (float*)d_out;

    hipMemsetAsync(d_ws, 0, 31232, stream);
    k_ce<<<B_N / 256, 256, 0, stream>>>(logits, labels, ws);
    k_cent<<<dim3(3, 64), 256, 0, stream>>>(emb, labels, ws);
    k_enorm<<<B_N / 4, 256, 0, stream>>>(emb, enorm);
    k_taml<<<dim3(32, 32), 256, 0, stream>>>(enorm, labels, topo, ws);
    k_tals<<<1, 128, 0, stream>>>(topo, ws, out);
}

// Round 3
// 199.492 us; speedup vs baseline: 1.1131x; 1.1131x over previous
//
#include <hip/hip_runtime.h>
#include <hip/hip_bf16.h>
#include <math.h>

#define B_N 4096
#define D_N 768
#define C_N 10
#define LDP 72   // BK=64 rows padded 64->72 elems (144B stride): fragment reads 2-way bank = free

typedef short bf16x8 __attribute__((ext_vector_type(8)));
typedef float f32x4 __attribute__((ext_vector_type(4)));

// ws layout (floats):
//   [0] ce_sum   [1] taml_sum
//   [8..18)   counts[10]
//   [32..32+7680)  class sums [10][768]
// byte offset 65536: enorm bf16 [4096*768]  (6291456 bytes)

static __device__ __forceinline__ unsigned short bf16bits(float f, float s) {
    __hip_bfloat16 h = __float2bfloat16(f * s);
    return *(unsigned short*)&h;
}

// ---------------- merged prep: CE + histogram | class sums | row-normalize ----------------
// blocks [0,16): CE over 4096 rows
// blocks [16,208): per-class segment sums (3 col-chunks x 64 row-chunks)
// blocks [208,1232): enorm, 4 rows/block (wave per row)
__global__ void k_prep(const float* __restrict__ logits,
                       const int* __restrict__ labels,
                       const float* __restrict__ emb,
                       float* __restrict__ ws,
                       __hip_bfloat16* __restrict__ enorm) {
    __shared__ float red[256];
    __shared__ float cnt[C_N];
    int bb = blockIdx.x;
    int t = threadIdx.x;

    if (bb < 16) {
        // ---- CE + label histogram ----
        if (t < C_N) cnt[t] = 0.f;
        __syncthreads();
        int row = bb * 256 + t;
        int lab = labels[row];
        const float* lp = logits + (size_t)row * C_N;
        float m = lp[0];
#pragma unroll
        for (int c = 1; c < C_N; ++c) m = fmaxf(m, lp[c]);
        float s = 0.f;
#pragma unroll
        for (int c = 0; c < C_N; ++c) s += __expf(lp[c] - m);
        float val = (m + __logf(s)) - lp[lab];
        atomicAdd(&cnt[lab], 1.0f);
        red[t] = val;
        __syncthreads();
        for (int off = 128; off; off >>= 1) {
            if (t < off) red[t] += red[t + off];
            __syncthreads();
        }
        if (t == 0) atomicAdd(&ws[0], red[0]);
        if (t < C_N) atomicAdd(&ws[8 + t], cnt[t]);
    } else if (bb < 208) {
        // ---- per-class segment sums: register accumulators ----
        int bx = (bb - 16) % 3, by = (bb - 16) / 3;
        int col = bx * 256 + t;
        int rbase = by * 64;
        float a[C_N];
#pragma unroll
        for (int c = 0; c < C_N; ++c) a[c] = 0.f;
        const float* p = emb + (size_t)rbase * D_N + col;
#pragma unroll 4
        for (int rr = 0; rr < 64; ++rr) {
            int lab = labels[rbase + rr];
            float v = p[(size_t)rr * D_N];
#pragma unroll
            for (int c = 0; c < C_N; ++c) a[c] += (lab == c) ? v : 0.f;
        }
        float* sums = ws + 32;
#pragma unroll
        for (int c = 0; c < C_N; ++c) atomicAdd(&sums[c * D_N + col], a[c]);
    } else {
        // ---- row-normalize -> bf16, wave per row ----
        int w = t >> 6, lane = t & 63;
        int row = (bb - 208) * 4 + w;
        const float4* src = (const float4*)(emb + (size_t)row * D_N);
        float4 x0 = src[lane];
        float4 x1 = src[lane + 64];
        float4 x2 = src[lane + 128];
        float ss = x0.x * x0.x + x0.y * x0.y + x0.z * x0.z + x0.w * x0.w
                 + x1.x * x1.x + x1.y * x1.y + x1.z * x1.z + x1.w * x1.w
                 + x2.x * x2.x + x2.y * x2.y + x2.z * x2.z + x2.w * x2.w;
#pragma unroll
        for (int off = 32; off; off >>= 1) ss += __shfl_xor(ss, off, 64);
        float inv = 1.0f / fmaxf(sqrtf(ss), 1e-12f);
        ushort4* dst = (ushort4*)(enorm + (size_t)row * D_N);
        ushort4 u0, u1, u2;
        u0.x = bf16bits(x0.x, inv); u0.y = bf16bits(x0.y, inv);
        u0.z = bf16bits(x0.z, inv); u0.w = bf16bits(x0.w, inv);
        u1.x = bf16bits(x1.x, inv); u1.y = bf16bits(x1.y, inv);
        u1.z = bf16bits(x1.z, inv); u1.w = bf16bits(x1.w, inv);
        u2.x = bf16bits(x2.x, inv); u2.y = bf16bits(x2.y, inv);
        u2.z = bf16bits(x2.z, inv); u2.w = bf16bits(x2.w, inv);
        dst[lane]       = u0;
        dst[lane + 64]  = u1;
        dst[lane + 128] = u2;
    }
}

// ---------------- fused TAML GEMM ----------------
// 128x128 tile, BK=64, padded LDS (LDP=72), register-prefetch pipeline.
// __launch_bounds__(256,2): 256-VGPR budget so prefetch regs don't spill.
__global__ __launch_bounds__(256, 2) void k_taml(const __hip_bfloat16* __restrict__ E,
                                                 const int* __restrict__ labels,
                                                 const float* __restrict__ topo,
                                                 float* __restrict__ ws) {
    int bi = blockIdx.y, bj = blockIdx.x;
    if (bj < bi) return;   // uniform exit, before any barrier

    __shared__ __hip_bfloat16 As[128 * LDP];
    __shared__ __hip_bfloat16 Bs[128 * LDP];
    __shared__ int lA[128], lB[128];
    __shared__ float topo_s[C_N * C_N];
    __shared__ float wsum[4];

    int t = threadIdx.x;
    int ib0 = bi * 128, jb0 = bj * 128;
    if (t < 128) lA[t] = labels[ib0 + t];
    else         lB[t - 128] = labels[jb0 + t - 128];
    if (t < C_N * C_N) topo_s[t] = topo[t];

    int w = t >> 6, lane = t & 63;
    int quad = lane >> 4, m16 = lane & 15;
    int wrow = (w >> 1) * 64, wcol = (w & 1) * 64;

    f32x4 acc[4][4];
    f32x4 z = {0.f, 0.f, 0.f, 0.f};
#pragma unroll
    for (int mt = 0; mt < 4; ++mt)
#pragma unroll
        for (int nt = 0; nt < 4; ++nt) acc[mt][nt] = z;

    // staging: 4 threads per row; thread covers rows {r2, r2+64}, 16 elems (2 float4) each.
    // Lanes 0..3 cover 128B contiguous of one row -> coalesced 128B segments.
    int r2 = t >> 2, q = t & 3;
    const __hip_bfloat16* baseA = E + (size_t)(ib0 + r2) * D_N + q * 16;
    const __hip_bfloat16* baseB = E + (size_t)(jb0 + r2) * D_N + q * 16;
    float4* wA0 = (float4*)(As + r2 * LDP + q * 16);
    float4* wA1 = (float4*)(As + (r2 + 64) * LDP + q * 16);
    float4* wB0 = (float4*)(Bs + r2 * LDP + q * 16);
    float4* wB1 = (float4*)(Bs + (r2 + 64) * LDP + q * 16);

    float4 pa[4], pb[4];
#define LOAD_TILE(kt)                                                              \
    {                                                                              \
        const float4* a0 = (const float4*)(baseA + (kt) * 64);                     \
        const float4* a1 = (const float4*)(baseA + (size_t)64 * D_N + (kt) * 64);  \
        const float4* b0 = (const float4*)(baseB + (kt) * 64);                     \
        const float4* b1 = (const float4*)(baseB + (size_t)64 * D_N + (kt) * 64);  \
        pa[0] = a0[0]; pa[1] = a0[1]; pa[2] = a1[0]; pa[3] = a1[1];                \
        pb[0] = b0[0]; pb[1] = b0[1]; pb[2] = b1[0]; pb[3] = b1[1];                \
    }
#define STORE_TILE()                                                               \
    {                                                                              \
        wA0[0] = pa[0]; wA0[1] = pa[1]; wA1[0] = pa[2]; wA1[1] = pa[3];            \
        wB0[0] = pb[0]; wB0[1] = pb[1]; wB1[0] = pb[2]; wB1[1] = pb[3];            \
    }

    LOAD_TILE(0);
    STORE_TILE();

    for (int kt = 0; kt < 12; ++kt) {
        __syncthreads();
        if (kt < 11) LOAD_TILE(kt + 1);
#pragma unroll
        for (int ks = 0; ks < 2; ++ks) {
            bf16x8 af[4], bfr[4];
#pragma unroll
            for (int x = 0; x < 4; ++x) {
                af[x]  = *(const bf16x8*)(As + (wrow + x * 16 + m16) * LDP + ks * 32 + quad * 8);
                bfr[x] = *(const bf16x8*)(Bs + (wcol + x * 16 + m16) * LDP + ks * 32 + quad * 8);
            }
#pragma unroll
            for (int mt = 0; mt < 4; ++mt)
#pragma unroll
                for (int nt = 0; nt < 4; ++nt)
                    acc[mt][nt] = __builtin_amdgcn_mfma_f32_16x16x32_bf16(
                        af[mt], bfr[nt], acc[mt][nt], 0, 0, 0);
        }
        __syncthreads();
        if (kt < 11) STORE_TILE();
    }

    // epilogue: relu(sim - 1 + margin) over valid (li!=lj) upper-tri pairs, x2
    float local = 0.f;
#pragma unroll
    for (int mt = 0; mt < 4; ++mt) {
#pragma unroll
        for (int nt = 0; nt < 4; ++nt) {
#pragma unroll
            for (int reg = 0; reg < 4; ++reg) {
                int il = wrow + mt * 16 + quad * 4 + reg;
                int jl = wcol + nt * 16 + m16;
                int gi = ib0 + il, gj = jb0 + jl;
                int li = lA[il], lj = lB[jl];
                float v = acc[mt][nt][reg] - 1.0f + topo_s[li * C_N + lj];
                if (li != lj && gi < gj && v > 0.f) local += v;
            }
        }
    }
    local *= 2.0f;

#pragma unroll
    for (int off = 32; off; off >>= 1) local += __shfl_down(local, off, 64);
    if (lane == 0) wsum[w] = local;
    __syncthreads();
    if (t == 0) atomicAdd(&ws[1], wsum[0] + wsum[1] + wsum[2] + wsum[3]);
}

// ---------------- TALS + nvalid + final combine ----------------
__global__ void k_tals(const float* __restrict__ topo, float* __restrict__ ws,
                       float* __restrict__ out) {
    __shared__ float cents[C_N * 769];
    __shared__ float edist[C_N * C_N];
    __shared__ float cnt_s[C_N];
    int t = threadIdx.x;   // 128 threads
    const float* counts = ws + 8;
    const float* sums = ws + 32;
    if (t < C_N) cnt_s[t] = counts[t];
    __syncthreads();
    for (int idx = t; idx < C_N * D_N; idx += 128) {
        int c = idx / D_N, d = idx - c * D_N;
        cents[c * 769 + d] = sums[idx] / fmaxf(cnt_s[c], 1.0f);
    }
    __syncthreads();
    if (t < C_N * C_N) {
        int i = t / C_N, j = t - (t / C_N) * C_N;
        float s = 0.f;
        for (int d = 0; d < D_N; ++d) {
            float diff = cents[i * 769 + d] - cents[j * 769 + d];
            s += diff * diff;
        }
        edist[t] = sqrtf(s + 1e-12f);
    }
    __syncthreads();
    if (t == 0) {
        float mx = 0.f;
        for (int p = 0; p < C_N * C_N; ++p) mx = fmaxf(mx, edist[p]);
        float inv = 1.0f / (mx + 1e-8f);
        float accv = 0.f;
        for (int p = 0; p < C_N * C_N; ++p) {
            float d = edist[p] * inv - topo[p];
            accv += d * d;
        }
        float tals = accv * (1.0f / (C_N * C_N));
        float s2 = 0.f;
        for (int c = 0; c < C_N; ++c) s2 += cnt_s[c] * cnt_s[c];
        float nvalid = (float)B_N * (float)B_N - s2;
        float ce   = ws[0] / (float)B_N;
        float taml = ws[1] / fmaxf(nvalid, 1.0f);
        out[0] = ce + 0.5f * tals + 0.5f * taml;
        out[1] = ce;
        out[2] = tals;
        out[3] = taml;
    }
}

extern "C" void kernel_launch(void* const* d_in, const int* in_sizes, int n_in,
                              void* d_out, int out_size, void* d_ws, size_t ws_size,
                              hipStream_t stream) {
    const float* logits = (const float*)d_in[0];
    const int*   labels = (const int*)d_in[1];
    const float* emb    = (const float*)d_in[2];
    const float* topo   = (const float*)d_in[3];
    float* ws = (float*)d_ws;
    __hip_bfloat16* enorm = (__hip_bfloat16*)((char*)d_ws + 65536);
    float* out = (float*)d_out;

    hipMemsetAsync(d_ws, 0, 31232, stream);
    k_prep<<<1232, 256, 0, stream>>>(logits, labels, emb, ws, enorm);
    k_taml<<<dim3(32, 32), 256, 0, stream>>>(enorm, labels, topo, ws);
    k_tals<<<1, 128, 0, stream>>>(topo, ws, out);
}

// Round 4
// 143.294 us; speedup vs baseline: 1.5497x; 1.3922x over previous
//
#include <hip/hip_runtime.h>
#include <hip/hip_bf16.h>
#include <math.h>

#define B_N 4096
#define D_N 768
#define C_N 10

typedef short bf16x8 __attribute__((ext_vector_type(8)));
typedef float f32x4 __attribute__((ext_vector_type(4)));

// ws layout (floats):
//   [0] ce_sum   [1] taml_sum
//   [8..18)   counts[10]
//   [32..32+7680)  class sums [10][768]
// byte offset 65536: enorm bf16 [4096*768]  (6291456 bytes)

typedef __attribute__((address_space(1))) const void gvoid;
typedef __attribute__((address_space(3))) void lvoid;

static __device__ __forceinline__ void gl2lds16(const void* g, void* l) {
    // async global->LDS, 16B per lane, dest = l + lane*16 (wave-uniform l)
    __builtin_amdgcn_global_load_lds((gvoid*)g, (lvoid*)l, 16, 0, 0);
}

static __device__ __forceinline__ unsigned short bf16bits(float f, float s) {
    __hip_bfloat16 h = __float2bfloat16(f * s);
    return *(unsigned short*)&h;
}

// ---------------- merged prep: CE + histogram | class sums | row-normalize ----------------
// blocks [0,16): CE; [16,208): class segment sums; [208,1232): enorm (wave/row)
__global__ void k_prep(const float* __restrict__ logits,
                       const int* __restrict__ labels,
                       const float* __restrict__ emb,
                       float* __restrict__ ws,
                       __hip_bfloat16* __restrict__ enorm) {
    __shared__ float red[256];
    __shared__ float cnt[C_N];
    int bb = blockIdx.x;
    int t = threadIdx.x;

    if (bb < 16) {
        if (t < C_N) cnt[t] = 0.f;
        __syncthreads();
        int row = bb * 256 + t;
        int lab = labels[row];
        const float* lp = logits + (size_t)row * C_N;
        float m = lp[0];
#pragma unroll
        for (int c = 1; c < C_N; ++c) m = fmaxf(m, lp[c]);
        float s = 0.f;
#pragma unroll
        for (int c = 0; c < C_N; ++c) s += __expf(lp[c] - m);
        float val = (m + __logf(s)) - lp[lab];
        atomicAdd(&cnt[lab], 1.0f);
        red[t] = val;
        __syncthreads();
        for (int off = 128; off; off >>= 1) {
            if (t < off) red[t] += red[t + off];
            __syncthreads();
        }
        if (t == 0) atomicAdd(&ws[0], red[0]);
        if (t < C_N) atomicAdd(&ws[8 + t], cnt[t]);
    } else if (bb < 208) {
        int bx = (bb - 16) % 3, by = (bb - 16) / 3;
        int col = bx * 256 + t;
        int rbase = by * 64;
        float a[C_N];
#pragma unroll
        for (int c = 0; c < C_N; ++c) a[c] = 0.f;
        const float* p = emb + (size_t)rbase * D_N + col;
#pragma unroll 4
        for (int rr = 0; rr < 64; ++rr) {
            int lab = labels[rbase + rr];
            float v = p[(size_t)rr * D_N];
#pragma unroll
            for (int c = 0; c < C_N; ++c) a[c] += (lab == c) ? v : 0.f;
        }
        float* sums = ws + 32;
#pragma unroll
        for (int c = 0; c < C_N; ++c) atomicAdd(&sums[c * D_N + col], a[c]);
    } else {
        int w = t >> 6, lane = t & 63;
        int row = (bb - 208) * 4 + w;
        const float4* src = (const float4*)(emb + (size_t)row * D_N);
        float4 x0 = src[lane];
        float4 x1 = src[lane + 64];
        float4 x2 = src[lane + 128];
        float ss = x0.x * x0.x + x0.y * x0.y + x0.z * x0.z + x0.w * x0.w
                 + x1.x * x1.x + x1.y * x1.y + x1.z * x1.z + x1.w * x1.w
                 + x2.x * x2.x + x2.y * x2.y + x2.z * x2.z + x2.w * x2.w;
#pragma unroll
        for (int off = 32; off; off >>= 1) ss += __shfl_xor(ss, off, 64);
        float inv = 1.0f / fmaxf(sqrtf(ss), 1e-12f);
        ushort4* dst = (ushort4*)(enorm + (size_t)row * D_N);
        ushort4 u0, u1, u2;
        u0.x = bf16bits(x0.x, inv); u0.y = bf16bits(x0.y, inv);
        u0.z = bf16bits(x0.z, inv); u0.w = bf16bits(x0.w, inv);
        u1.x = bf16bits(x1.x, inv); u1.y = bf16bits(x1.y, inv);
        u1.z = bf16bits(x1.z, inv); u1.w = bf16bits(x1.w, inv);
        u2.x = bf16bits(x2.x, inv); u2.y = bf16bits(x2.y, inv);
        u2.z = bf16bits(x2.z, inv); u2.w = bf16bits(x2.w, inv);
        dst[lane]       = u0;
        dst[lane + 64]  = u1;
        dst[lane + 128] = u2;
    }
}

// ---------------- fused TAML GEMM (m97 structure) ----------------
// 128x128 tile, BK=32, global_load_lds width-16 staging (no staging VGPRs),
// XOR-swizzled LDS slots (bank aliasing 8-way -> 4-way), 2-barrier K-loop.
__global__ __launch_bounds__(256) void k_taml(const __hip_bfloat16* __restrict__ E,
                                              const int* __restrict__ labels,
                                              const float* __restrict__ topo,
                                              float* __restrict__ ws) {
    int bi = blockIdx.y, bj = blockIdx.x;
    if (bj < bi) return;   // uniform exit, before any barrier

    __shared__ __align__(16) __hip_bfloat16 As[128 * 32];
    __shared__ __align__(16) __hip_bfloat16 Bs[128 * 32];
    __shared__ int lA[128], lB[128];
    __shared__ float topo_s[C_N * C_N];
    __shared__ float wsum[4];

    int t = threadIdx.x;
    int ib0 = bi * 128, jb0 = bj * 128;
    if (t < 128) lA[t] = labels[ib0 + t];
    else         lB[t - 128] = labels[jb0 + t - 128];
    if (t < C_N * C_N) topo_s[t] = topo[t];

    int w = t >> 6, lane = t & 63;
    int quad = lane >> 4, m16 = lane & 15;
    int wrow = (w >> 1) * 64, wcol = (w & 1) * 64;
    int qsw = (quad ^ (m16 & 3)) * 8;   // swizzled fragment k-slot (elems)

    f32x4 acc[4][4];
    f32x4 z = {0.f, 0.f, 0.f, 0.f};
#pragma unroll
    for (int mt = 0; mt < 4; ++mt)
#pragma unroll
        for (int nt = 0; nt < 4; ++nt) acc[mt][nt] = z;

    // staging: wave w owns 1024B chunks {w, w+4} of each tile.
    // chunk h = rows 16h..16h+15; lane: r = lane>>2, c = lane&3;
    // lane fetches global k-slot (c ^ (r&3)) so LDS slot c holds swizzled data.
    int rl = lane >> 2, cs = lane & 3;
    int csw = (cs ^ (rl & 3)) * 8;   // elems within BK
    const __hip_bfloat16* gA0 = E + (size_t)(ib0 + 16 * w + rl) * D_N + csw;
    const __hip_bfloat16* gA1 = E + (size_t)(ib0 + 16 * (w + 4) + rl) * D_N + csw;
    const __hip_bfloat16* gB0 = E + (size_t)(jb0 + 16 * w + rl) * D_N + csw;
    const __hip_bfloat16* gB1 = E + (size_t)(jb0 + 16 * (w + 4) + rl) * D_N + csw;
    char* lA0 = (char*)As + w * 1024;         // wave-uniform LDS bases
    char* lA1 = (char*)As + (w + 4) * 1024;
    char* lB0 = (char*)Bs + w * 1024;
    char* lB1 = (char*)Bs + (w + 4) * 1024;

    for (int kt = 0; kt < 24; ++kt) {
        __syncthreads();                       // prev compute done, LDS reusable
        gl2lds16(gA0 + kt * 32, lA0);
        gl2lds16(gA1 + kt * 32, lA1);
        gl2lds16(gB0 + kt * 32, lB0);
        gl2lds16(gB1 + kt * 32, lB1);
        __syncthreads();                       // compiler drains vmcnt before barrier

        bf16x8 af[4], bfr[4];
#pragma unroll
        for (int x = 0; x < 4; ++x) {
            af[x]  = *(const bf16x8*)(As + (wrow + x * 16 + m16) * 32 + qsw);
            bfr[x] = *(const bf16x8*)(Bs + (wcol + x * 16 + m16) * 32 + qsw);
        }
#pragma unroll
        for (int mt = 0; mt < 4; ++mt)
#pragma unroll
            for (int nt = 0; nt < 4; ++nt)
                acc[mt][nt] = __builtin_amdgcn_mfma_f32_16x16x32_bf16(
                    af[mt], bfr[nt], acc[mt][nt], 0, 0, 0);
    }

    // epilogue: relu(sim - 1 + margin) over valid (li!=lj) upper-tri pairs, x2
    float local = 0.f;
#pragma unroll
    for (int mt = 0; mt < 4; ++mt) {
#pragma unroll
        for (int nt = 0; nt < 4; ++nt) {
#pragma unroll
            for (int reg = 0; reg < 4; ++reg) {
                int il = wrow + mt * 16 + quad * 4 + reg;
                int jl = wcol + nt * 16 + m16;
                int gi = ib0 + il, gj = jb0 + jl;
                int li = lA[il], lj = lB[jl];
                float v = acc[mt][nt][reg] - 1.0f + topo_s[li * C_N + lj];
                if (li != lj && gi < gj && v > 0.f) local += v;
            }
        }
    }
    local *= 2.0f;

#pragma unroll
    for (int off = 32; off; off >>= 1) local += __shfl_down(local, off, 64);
    if (lane == 0) wsum[w] = local;
    __syncthreads();
    if (t == 0) atomicAdd(&ws[1], wsum[0] + wsum[1] + wsum[2] + wsum[3]);
}

// ---------------- TALS + nvalid + final combine (parallel) ----------------
__global__ void k_tals(const float* __restrict__ topo, float* __restrict__ ws,
                       float* __restrict__ out) {
    __shared__ float cents[C_N * D_N];   // 30 KB
    __shared__ float ed[112];
    __shared__ float cnt_s[C_N];
    int t = threadIdx.x;   // 256 threads = 4 waves
    int w = t >> 6, lane = t & 63;
    const float* counts = ws + 8;
    const float* sums = ws + 32;
    if (t < C_N) cnt_s[t] = counts[t];
    __syncthreads();
    for (int idx = t; idx < C_N * D_N; idx += 256) {
        int c = idx / D_N;
        cents[idx] = sums[idx] / fmaxf(cnt_s[c], 1.0f);
    }
    __syncthreads();
    // 100 pairs: wave w handles p = 25w .. 25w+24; lanes split D
    for (int pp = 0; pp < 25; ++pp) {
        int p = w * 25 + pp;
        int i = p / C_N, j = p - (p / C_N) * C_N;
        const float* ci = cents + i * D_N;
        const float* cj = cents + j * D_N;
        float s = 0.f;
        for (int d = lane; d < D_N; d += 64) {
            float diff = ci[d] - cj[d];
            s += diff * diff;
        }
#pragma unroll
        for (int off = 32; off; off >>= 1) s += __shfl_xor(s, off, 64);
        if (lane == 0) ed[p] = sqrtf(s + 1e-12f);
    }
    __syncthreads();
    if (w == 0) {
        float e0 = ed[lane];                                 // p = lane (0..63)
        float e1 = (lane < 36) ? ed[lane + 64] : 0.f;        // p = 64..99
        float mx = fmaxf(e0, e1);
#pragma unroll
        for (int off = 32; off; off >>= 1) mx = fmaxf(mx, __shfl_xor(mx, off, 64));
        float inv = 1.0f / (mx + 1e-8f);
        float d0 = e0 * inv - topo[lane];
        float s = d0 * d0;
        if (lane < 36) {
            float d1 = e1 * inv - topo[lane + 64];
            s += d1 * d1;
        }
#pragma unroll
        for (int off = 32; off; off >>= 1) s += __shfl_xor(s, off, 64);
        if (lane == 0) {
            float tals = s * (1.0f / (C_N * C_N));
            float s2 = 0.f;
#pragma unroll
            for (int c = 0; c < C_N; ++c) s2 += cnt_s[c] * cnt_s[c];
            float nvalid = (float)B_N * (float)B_N - s2;
            float ce   = ws[0] / (float)B_N;
            float taml = ws[1] / fmaxf(nvalid, 1.0f);
            out[0] = ce + 0.5f * tals + 0.5f * taml;
            out[1] = ce;
            out[2] = tals;
            out[3] = taml;
        }
    }
}

extern "C" void kernel_launch(void* const* d_in, const int* in_sizes, int n_in,
                              void* d_out, int out_size, void* d_ws, size_t ws_size,
                              hipStream_t stream) {
    const float* logits = (const float*)d_in[0];
    const int*   labels = (const int*)d_in[1];
    const float* emb    = (const float*)d_in[2];
    const float* topo   = (const float*)d_in[3];
    float* ws = (float*)d_ws;
    __hip_bfloat16* enorm = (__hip_bfloat16*)((char*)d_ws + 65536);
    float* out = (float*)d_out;

    hipMemsetAsync(d_ws, 0, 31232, stream);
    k_prep<<<1232, 256, 0, stream>>>(logits, labels, emb, ws, enorm);
    k_taml<<<dim3(32, 32), 256, 0, stream>>>(enorm, labels, topo, ws);
    k_tals<<<1, 256, 0, stream>>>(topo, ws, out);
}